// Round 5
// baseline (415.688 us; speedup 1.0000x reference)
//
#include <hip/hip_runtime.h>
#include <hip/hip_bf16.h>
#include <math.h>

typedef __bf16 bf16_t;
typedef __bf16 bf16x4 __attribute__((ext_vector_type(4)));
typedef __bf16 bf16x8 __attribute__((ext_vector_type(8)));
typedef float floatx4 __attribute__((ext_vector_type(4)));

#define N_NODES 32768
#define K_CENT  2048
#define D_DIM   512

// ---------------- prep: fp32 row -> bf16 row + sum of squares ----------------
__global__ void prep_rows_kernel(const float* __restrict__ src,
                                 bf16_t* __restrict__ dst,
                                 float* __restrict__ sq) {
  const int w = threadIdx.x >> 6;
  const int l = threadIdx.x & 63;
  const int row = blockIdx.x * 4 + w;
  const float4* s = (const float4*)(src + (size_t)row * D_DIM);
  float4 f0 = s[l];
  float4 f1 = s[64 + l];
  bf16x4 b0 = { (bf16_t)f0.x, (bf16_t)f0.y, (bf16_t)f0.z, (bf16_t)f0.w };
  bf16x4 b1 = { (bf16_t)f1.x, (bf16_t)f1.y, (bf16_t)f1.z, (bf16_t)f1.w };
  bf16x4* d = (bf16x4*)(dst + (size_t)row * D_DIM);
  d[l] = b0;
  d[64 + l] = b1;
  float v = f0.x*f0.x + f0.y*f0.y + f0.z*f0.z + f0.w*f0.w
          + f1.x*f1.x + f1.y*f1.y + f1.z*f1.z + f1.w*f1.w;
  #pragma unroll
  for (int s2 = 32; s2; s2 >>= 1) v += __shfl_xor(v, s2);
  if (l == 0) sq[row] = v;
}

// ---------------- mask sum -> single scalar ----------------
__global__ void mask_sum_kernel(const float* __restrict__ m,
                                float* __restrict__ out, int n) {
  float v = 0.f;
  for (int i = blockIdx.x * blockDim.x + threadIdx.x; i < n;
       i += gridDim.x * blockDim.x)
    v += m[i];
  #pragma unroll
  for (int s = 32; s; s >>= 1) v += __shfl_xor(v, s);
  __shared__ float red[4];
  if ((threadIdx.x & 63) == 0) red[threadIdx.x >> 6] = v;
  __syncthreads();
  if (threadIdx.x == 0) atomicAdd(out, red[0] + red[1] + red[2] + red[3]);
}

// ---------------- async global -> LDS, 16B per lane ----------------
__device__ inline void gld_lds16(const void* g, void* l) {
  __builtin_amdgcn_global_load_lds(
      (__attribute__((address_space(1))) void*)const_cast<void*>(g),
      (__attribute__((address_space(3))) void*)l, 16, 0, 0);
}

// ---------------- GEMM + fused distance epilogue ----------------
// m97 structure: 128x128 tile, BK=64, SINGLE-buffered 32 KiB LDS, 4 waves,
// ~4 blocks/CU resident -> inter-block overlap hides the per-tile vmcnt(0)
// drain (m114 mechanism). Plus counter-verified fixes from Round 2:
// bank-conflict source/read swizzle (conflicts 2.5e7 -> 0) and bijective
// XCD block remap (FETCH 140 MB -> 25 MB). Plain stores (NT regressed).
__global__ void __launch_bounds__(256)
gemm_dist_kernel(const bf16_t* __restrict__ A,
                 const bf16_t* __restrict__ B,
                 const float* __restrict__ x2,
                 const float* __restrict__ c2,
                 const float* __restrict__ mask,
                 float* __restrict__ out_node,
                 float* __restrict__ colsum) {
  // row-major [128][64] bf16 tiles (128 B rows = 8 chunks of 16 B).
  // LDS layout linear (gld_lds writes base+lane*16); LDS(row, c) holds DATA
  // chunk c ^ (row&7): staging pre-swizzles the GLOBAL source chunk, reads
  // XOR the chunk index -> conflict-free (verified 0 in Round 2).
  __shared__ __align__(16) bf16_t sA[128 * 64];
  __shared__ __align__(16) bf16_t sB[128 * 64];

  const int t = threadIdx.x;
  const int w = t >> 6;        // wave 0..3
  const int l = t & 63;

  // XCD-aware bijective remap: 4096 blocks = 8 XCDs x 512.
  // XCD x owns bm in [x*32, (x+1)*32) x all 16 bn -> A panel stays in one L2.
  const int wg = (blockIdx.x & 7) * 512 + (blockIdx.x >> 3);
  const int bm = wg >> 4;      // 0..255  (node-row block)
  const int bn = wg & 15;      // 0..15   (centroid block)

  const int wm = (w >> 1) * 64;
  const int wn = (w & 1) * 64;
  const int lr = l & 15;           // A-row / B-col within 16x16 tile
  const int hi = l >> 4;           // k-group within 32 (8 elems each)

  floatx4 acc[4][4] = {};

  // staging: pass p loads row p*32 + w*8 + (l>>3); row&7 == l>>3 for every
  // pass, so the pre-swizzled source chunk is (l&7)^(l>>3) throughout.
  const int srow = w * 8 + (l >> 3);
  const int scol = ((l & 7) ^ (l >> 3)) * 8;   // pre-swizzled source chunk
  const bf16_t* gA = A + (size_t)(bm * 128 + srow) * D_DIM + scol;
  const bf16_t* gB = B + (size_t)(bn * 128 + srow) * D_DIM + scol;
  char* lA = (char*)sA + w * 1024;  // wave-uniform base; HW adds lane*16
  char* lB = (char*)sB + w * 1024;

  for (int kt = 0; kt < D_DIM; kt += 64) {
    #pragma unroll
    for (int p = 0; p < 4; ++p) {
      gld_lds16(gA + (size_t)(p * 32) * D_DIM + kt, lA + p * 4096);
      gld_lds16(gB + (size_t)(p * 32) * D_DIM + kt, lB + p * 4096);
    }
    __syncthreads();   // vmcnt(0) drain -- hidden by ~4 co-resident blocks
    #pragma unroll
    for (int ks = 0; ks < 2; ++ks) {           // k-slice of 32
      bf16x8 af[4], bfr[4];
      #pragma unroll
      for (int i = 0; i < 4; ++i) {
        const int r = wm + i * 16 + lr;
        const int c = ((ks * 4 + hi) ^ (lr & 7)) * 16;  // swizzled read chunk
        af[i] = *(const bf16x8*)((const char*)sA + r * 128 + c);
      }
      #pragma unroll
      for (int j = 0; j < 4; ++j) {
        const int r = wn + j * 16 + lr;
        const int c = ((ks * 4 + hi) ^ (lr & 7)) * 16;
        bfr[j] = *(const bf16x8*)((const char*)sB + r * 128 + c);
      }
      #pragma unroll
      for (int i = 0; i < 4; ++i) {
        #pragma unroll
        for (int j = 0; j < 4; ++j)
          acc[i][j] = __builtin_amdgcn_mfma_f32_16x16x32_bf16(
              af[i], bfr[j], acc[i][j], 0, 0, 0);
      }
    }
    __syncthreads();
  }

  // ---- epilogue: C/D layout col = lane&15, row = (lane>>4)*4 + reg ----
  const int col0 = bn * 128 + wn;
  float c2v[4];
  #pragma unroll
  for (int j = 0; j < 4; ++j) c2v[j] = c2[col0 + j * 16 + lr];

  float colacc[4] = {0.f, 0.f, 0.f, 0.f};
  #pragma unroll
  for (int i = 0; i < 4; ++i) {
    const int rbase = bm * 128 + wm + i * 16 + hi * 4;
    #pragma unroll
    for (int r = 0; r < 4; ++r) {
      const int row = rbase + r;
      const float xv = x2[row];
      const float mk = mask[row];
      float* orow = out_node + (size_t)row * K_CENT + col0 + lr;
      #pragma unroll
      for (int j = 0; j < 4; ++j) {
        float d2 = xv + c2v[j] - 2.0f * acc[i][j][r];
        float dist = sqrtf(fmaxf(d2, 1e-12f));
        float dm = dist * mk;
        orow[j * 16] = dm;            // plain store: L2 write-combining
        colacc[j] += dm;
      }
    }
  }

  // reduce column partials across the 4 row-groups of the wave
  #pragma unroll
  for (int j = 0; j < 4; ++j) {
    colacc[j] += __shfl_xor(colacc[j], 16);
    colacc[j] += __shfl_xor(colacc[j], 32);
  }
  // block-level reduce in LDS (reuse sA; safe: K-loop ended with a barrier)
  float* colbuf = (float*)sA;
  if (w < 2 && l < 16) {
    #pragma unroll
    for (int j = 0; j < 4; ++j) colbuf[wn + j * 16 + l] = colacc[j];
  }
  __syncthreads();
  if (w >= 2 && l < 16) {
    #pragma unroll
    for (int j = 0; j < 4; ++j) colbuf[wn + j * 16 + l] += colacc[j];
  }
  __syncthreads();
  if (t < 128) atomicAdd(&colsum[bn * 128 + t], colbuf[t]);
}

// ---------------- finalize: graph[k] = colsum[k] / masksum ----------------
__global__ void finalize_kernel(const float* __restrict__ colsum,
                                const float* __restrict__ msum,
                                float* __restrict__ out) {
  int k = blockIdx.x * 256 + threadIdx.x;
  out[k] = colsum[k] / msum[0];
}

extern "C" void kernel_launch(void* const* d_in, const int* in_sizes, int n_in,
                              void* d_out, int out_size, void* d_ws, size_t ws_size,
                              hipStream_t stream) {
  const float* node = (const float*)d_in[0];
  const float* mask = (const float*)d_in[1];
  const float* cent = (const float*)d_in[2];
  float* out_graph = (float*)d_out;            // [1, K] first in return order
  float* out_node  = out_graph + K_CENT;       // [1, N, K]

  char* ws = (char*)d_ws;
  size_t off = 0;
  bf16_t* Abf = (bf16_t*)(ws + off); off += (size_t)N_NODES * D_DIM * sizeof(bf16_t);
  bf16_t* Cbf = (bf16_t*)(ws + off); off += (size_t)K_CENT * D_DIM * sizeof(bf16_t);
  float* x2     = (float*)(ws + off); off += (size_t)N_NODES * sizeof(float);
  float* c2     = (float*)(ws + off); off += (size_t)K_CENT * sizeof(float);
  float* colsum = (float*)(ws + off); off += (size_t)K_CENT * sizeof(float);
  float* msum   = (float*)(ws + off); off += sizeof(float);

  hipMemsetAsync(colsum, 0, (K_CENT + 1) * sizeof(float), stream);

  prep_rows_kernel<<<N_NODES / 4, 256, 0, stream>>>(node, Abf, x2);
  prep_rows_kernel<<<K_CENT / 4, 256, 0, stream>>>(cent, Cbf, c2);
  mask_sum_kernel<<<64, 256, 0, stream>>>(mask, msum, N_NODES);
  gemm_dist_kernel<<<4096, 256, 0, stream>>>(
      Abf, Cbf, x2, c2, mask, out_node, colsum);
  finalize_kernel<<<K_CENT / 256, 256, 0, stream>>>(colsum, msum, out_graph);
}